// Round 1
// baseline (281.144 us; speedup 1.0000x reference)
//
#include <hip/hip_runtime.h>

#define NNODES 50000
#define NEDGES 800000
#define F 128
#define NREL 8
#define NOUT 1152   // 9*128: 8 relations + self-loop
#define NBKT 98     // ceil(50000 / 512) coarse buckets
#define BSH 9       // 512 nodes per bucket
#define NGRP 98     // ceil(50000 / 512) row-groups of 8x64
#define TPB 8       // 64-row tiles per block
#define GEMM_BLOCKS (8 * 9 * 13)   // 936 (XCD-swizzled: x=id&7, j=id>>3)
#define CSR_BLOCKS 196

typedef short bf16x8 __attribute__((ext_vector_type(8)));
typedef float f32x4 __attribute__((ext_vector_type(4)));
typedef float f32x2 __attribute__((ext_vector_type(2)));

__device__ __forceinline__ unsigned f2bf(float f) {  // RNE
  unsigned u = __float_as_uint(f);
  u += 0x7fffu + ((u >> 16) & 1u);
  return u >> 16;
}
__device__ __forceinline__ float bf2f(unsigned v) {
  return __uint_as_float(v << 16);
}

typedef __attribute__((address_space(3))) void lds_void;
typedef const __attribute__((address_space(1))) void glb_void;
__device__ __forceinline__ void gll16(const void* g, void* l) {
  // async global->LDS, 16B per lane; LDS dest = wave-uniform base + lane*16
  __builtin_amdgcn_global_load_lds(
      (glb_void*)(unsigned long long)g,
      (lds_void*)(unsigned)(unsigned long long)l, 16, 0, 0);
}

// ========== fused prep: chist | cvt | prepw(W1) | prepw(W2) =================
#define PREP_CHIST 196
#define PREP_CVT   12500   // 50000*128/2 / 256
#define PREP_W     576     // 1152*128 / 256
__global__ __launch_bounds__(256)
void k_prep(const int* __restrict__ dst, int* __restrict__ bcnt,
            const float* __restrict__ in_feat, ushort* __restrict__ feat0,
            const float* __restrict__ W1, const float* __restrict__ W1s,
            ushort* __restrict__ Wt1,
            const float* __restrict__ W2, const float* __restrict__ W2s,
            ushort* __restrict__ Wt2) {
  const int b = blockIdx.x, t = threadIdx.x;
  if (b < PREP_CHIST) {
    __shared__ int hist[NBKT];
    if (t < NBKT) hist[t] = 0;
    __syncthreads();
    int e0 = b * 4096;
#pragma unroll
    for (int i = 0; i < 16; ++i) {
      int e = e0 + t + i * 256;
      if (e < NEDGES) atomicAdd(&hist[dst[e] >> BSH], 1);
    }
    __syncthreads();
    if (t < NBKT && hist[t] > 0) atomicAdd(&bcnt[t], hist[t]);
  } else if (b < PREP_CHIST + PREP_CVT) {
    int i = (b - PREP_CHIST) * 256 + t;  // exactly 3.2M
    float2 v = ((const float2*)in_feat)[i];
    ((unsigned*)feat0)[i] = f2bf(v.x) | (f2bf(v.y) << 16);
  } else {
    int w2 = (b >= PREP_CHIST + PREP_CVT + PREP_W);
    int idx = (b - PREP_CHIST - PREP_CVT - (w2 ? PREP_W : 0)) * 256 + t;
    int n = idx >> 7, k = idx & 127;
    int r = n >> 7, c = n & 127;
    const float* Wr = w2 ? W2 : W1;
    const float* Ws = w2 ? W2s : W1s;
    float v = (r < NREL) ? Wr[((size_t)r * F + k) * F + c] : Ws[(size_t)k * F + c];
    (w2 ? Wt2 : Wt1)[idx] = (ushort)f2bf(v);
  }
}

// ================= CSR scan =================================================
__global__ __launch_bounds__(128)
void k_cscan(const int* __restrict__ bcnt, int* __restrict__ bbase,
             int* __restrict__ bcur, int* __restrict__ rowptr) {
  __shared__ int s[128];
  int t = threadIdx.x;
  int v = (t < NBKT) ? bcnt[t] : 0;
  s[t] = v;
  __syncthreads();
  for (int off = 1; off < 128; off <<= 1) {
    int x = (t >= off) ? s[t - off] : 0;
    __syncthreads();
    s[t] += x;
    __syncthreads();
  }
  if (t < NBKT) { bbase[t] = s[t] - v; bcur[t] = s[t] - v; }
  if (t == 0) rowptr[NNODES] = NEDGES;
}

__global__ __launch_bounds__(256)
void k_fsort(const int* __restrict__ ebuf, const int* __restrict__ bbase,
             const int* __restrict__ bcnt, int* __restrict__ rowptr,
             int* __restrict__ edata) {
  __shared__ int cnt[512];
  __shared__ int pos[512];
  __shared__ int ws2[256];
  const int b = blockIdx.x, t = threadIdx.x;
  const int beg = bbase[b], end = beg + bcnt[b];
  cnt[t] = 0; cnt[t + 256] = 0;
  __syncthreads();
  for (int e = beg + t; e < end; e += 256)
    atomicAdd(&cnt[((unsigned)ebuf[e]) >> 19], 1);
  __syncthreads();
  int a = cnt[2 * t], b2 = cnt[2 * t + 1];
  ws2[t] = a + b2;
  __syncthreads();
  for (int off = 1; off < 256; off <<= 1) {
    int x = (t >= off) ? ws2[t - off] : 0;
    __syncthreads();
    ws2[t] += x;
    __syncthreads();
  }
  int ep = ws2[t] - (a + b2);
  pos[2 * t] = ep;
  pos[2 * t + 1] = ep + a;
  __syncthreads();
  int node0 = b << BSH;
#pragma unroll
  for (int i = t; i < 512; i += 256) {
    int node = node0 + i;
    if (node < NNODES) rowptr[node] = beg + pos[i];
  }
  __syncthreads();
  for (int e = beg + t; e < end; e += 256) {
    int rec = ebuf[e];
    int c = ((unsigned)rec) >> 19;
    int lrank = atomicAdd(&pos[c], 1);
    int srcv = (rec >> 3) & 0xFFFF;
    int etv = rec & 7;
    edata[beg + lrank] = srcv * NOUT + etv * F;  // byte offset in fp8 xrs
  }
}

// ====== GEMM: xrs[50000][1152](fp8) = A[50000][128] @ Wt^T  (bf16 MFMA) =====
// R15 structure: pipelined multi-tile block (T3/T4). 256 thr / 4 waves.
// Block = one cb (128-feature slice) x 8 consecutive 64-row A-tiles.
// B (weights) hoisted to 64 VGPRs/lane once per block (L2-resident).
// A staged via global_load_lds into a 3-deep 16KB ring (48KB LDS ->
// 3 blocks/CU), source pre-swizzled (XOR r&15) so linear LDS write lands
// swizzled. Counted vmcnt (never 0 in loop): stages for t+1/t+2 stay in
// flight across barriers. Bit-identical accumulation order to R14.
// doCsr: blocks [0,196) instead run the coarse CSR scatter.
__global__ __launch_bounds__(256, 3)
void gemm_xrs(const ushort* __restrict__ A, const ushort* __restrict__ Wt,
              unsigned char* __restrict__ xrs, int doCsr,
              const int* __restrict__ src, const int* __restrict__ dst,
              const int* __restrict__ et, int* __restrict__ bcur,
              int* __restrict__ ebuf) {
  __shared__ uint4 As[3][1024];  // 3 x (64 rows x 16 uint4), xor-swizzled
  __shared__ int lhist[NBKT];
  __shared__ int lbase[NBKT];
  const int tid = threadIdx.x;

  if (doCsr && blockIdx.x < CSR_BLOCKS) {
    // ---- coarse scatter: record = (dst_local<<19)|(src<<3)|et ----
    if (tid < NBKT) lhist[tid] = 0;
    __syncthreads();
    int e0 = blockIdx.x * 4096;
    int rec[16], cc[16], lr[16];
#pragma unroll
    for (int i = 0; i < 16; ++i) {
      int e = e0 + tid + i * 256;
      if (e < NEDGES) {
        int d = dst[e];
        cc[i] = d >> BSH;
        rec[i] = ((d & 511) << 19) | (src[e] << 3) | et[e];
        lr[i] = atomicAdd(&lhist[cc[i]], 1);
      } else {
        cc[i] = -1;
      }
    }
    __syncthreads();
    if (tid < NBKT && lhist[tid] > 0) lbase[tid] = atomicAdd(&bcur[tid], lhist[tid]);
    __syncthreads();
#pragma unroll
    for (int i = 0; i < 16; ++i)
      if (cc[i] >= 0) ebuf[lbase[cc[i]] + lr[i]] = rec[i];
    return;
  }

  const int id = blockIdx.x - (doCsr ? CSR_BLOCKS : 0);
  const int x = id & 7, j = id >> 3;
  const int g = (j / 9) * 8 + x;   // row-group: 9 cbs of a group land on one XCD
  const int cb = j % 9;
  if (g >= NGRP) return;
  const int grow0 = g * (TPB * 64);

  const int lane = tid & 63;
  const int w = tid >> 6;                 // 0..3
  const int i16 = lane & 15, q = lane >> 4;
  const int mbase = (w & 1) * 32, nbase = (w >> 1) * 64;

  // ---- B fragments: 16 x dwordx4 per lane, held in regs for all 8 steps ----
  bf16x8 breg[4][4];
#pragma unroll
  for (int c = 0; c < 4; ++c)
#pragma unroll
    for (int ni = 0; ni < 4; ++ni)
      breg[c][ni] = *(const bf16x8*)(
          Wt + ((size_t)(cb * 128 + nbase + ni * 16 + i16)) * F + (c * 4 + q) * 8);

  // ---- A staging: 4 x gll16 per thread per 64-row tile ----
  // slot L = tid + i*256: r = L>>4, c4s = L&15; source col = c4s ^ (r&15)
  // (pre-swizzled source + linear LDS dest == swizzled tile; rule 21)
  auto stage = [&](int t) {
    uint4* buf = &As[t % 3][0];
#pragma unroll
    for (int i = 0; i < 4; ++i) {
      int L = tid + i * 256;
      int r = L >> 4, c4s = L & 15;
      int c4 = c4s ^ (r & 15);
      int agr = grow0 + t * 64 + r;
      if (agr >= NNODES) agr = NNODES - 1;
      gll16((const void*)(A + (size_t)agr * F + c4 * 8), (void*)(buf + L));
    }
  };

  stage(0);
  stage(1);

#pragma unroll
  for (int t = 0; t < TPB; ++t) {
    if (t + 2 < TPB) stage(t + 2);
    // exact counted waits: guarantee stage(t)'s 4 loads retired, keep
    // stage(t+1)/stage(t+2) (+ prior epilogue stores) in flight.
    if (t == 0)            asm volatile("s_waitcnt vmcnt(8)" ::: "memory");
    else if (t == 1)       asm volatile("s_waitcnt vmcnt(16)" ::: "memory");
    else if (t < TPB - 2)  asm volatile("s_waitcnt vmcnt(24)" ::: "memory");
    else if (t == TPB - 2) asm volatile("s_waitcnt vmcnt(20)" ::: "memory");
    else                   asm volatile("s_waitcnt vmcnt(16)" ::: "memory");
    __builtin_amdgcn_sched_barrier(0);
    __builtin_amdgcn_s_barrier();

    const uint4* buf = &As[t % 3][0];
    f32x4 acc[2][4];
#pragma unroll
    for (int a = 0; a < 2; ++a)
#pragma unroll
      for (int b = 0; b < 4; ++b) acc[a][b] = (f32x4)0.f;

#pragma unroll
    for (int c = 0; c < 4; ++c) {
      bf16x8 af[2];
#pragma unroll
      for (int mi = 0; mi < 2; ++mi) {
        int r = mbase + mi * 16 + i16;
        af[mi] = *(const bf16x8*)&buf[r * 16 + ((c * 4 + q) ^ i16)];
      }
      // Swapped operands: D[m=weight feature][n=node row]; same K-order as R14
#pragma unroll
      for (int mi = 0; mi < 2; ++mi)
#pragma unroll
        for (int ni = 0; ni < 4; ++ni)
          acc[mi][ni] = __builtin_amdgcn_mfma_f32_16x16x32_bf16(
              breg[c][ni], af[mi], acc[mi][ni], 0, 0, 0);
    }

    // all waves done reading buf[t%3] before it can be restaged (t+3)
    asm volatile("s_waitcnt lgkmcnt(0)" ::: "memory");
    __builtin_amdgcn_sched_barrier(0);
    __builtin_amdgcn_s_barrier();

    // Epilogue: lane holds nodes mbase+mi*16+i16, feats nbase+q*4+[0..3]+ni*16
    int row0t = grow0 + t * 64;
#pragma unroll
    for (int mi = 0; mi < 2; ++mi) {
      int row = row0t + mbase + mi * 16 + i16;
      bool ok = row < NNODES;
      size_t rb = (size_t)row * NOUT + cb * 128 + nbase + q * 4;
#pragma unroll
      for (int ni = 0; ni < 4; ++ni) {
        f32x4 v = acc[mi][ni];
        unsigned pk = 0;
        pk = __builtin_amdgcn_cvt_pk_fp8_f32(v[0], v[1], pk, false);
        pk = __builtin_amdgcn_cvt_pk_fp8_f32(v[2], v[3], pk, true);
        if (ok) *(unsigned*)(xrs + rb + ni * 16) = pk;
      }
    }
  }
}

// ========== aggregate: h_next[dst] = relu(sum_e xrs[edata] + self + b) ======
// Paired-edge: half-wave (32 lanes) per edge, 4B dword loads (full 128B row
// per half-wave), 8 pairs (16 edges) in flight, __shfl for offsets,
// __shfl_xor(32) merges halves. 12500 blocks x 4 nodes = 50000 exactly.
// hout != null: store bf16 h. pooled_p != null: LDS-reduce block's 4 nodes,
// atomicAdd into 64-slot-spread partials (pooling fused; h2 never written).
__global__ __launch_bounds__(256)
void k_aggregate(const unsigned char* __restrict__ xrs,
                 const int* __restrict__ rowptr, const int* __restrict__ edata,
                 const float* __restrict__ bias, ushort* __restrict__ hout,
                 float* __restrict__ pooled_p) {
  __shared__ float red[4][128];
  const int wv = threadIdx.x >> 6;
  const int node = blockIdx.x * 4 + wv;
  const int lane = threadIdx.x & 63;
  const int half = lane >> 5, sl = lane & 31;
  const int beg = rowptr[node], end = rowptr[node + 1];

  float a0 = 0.f, a1 = 0.f, a2 = 0.f, a3 = 0.f;
  // self-loop row (r=8), counted once by half 0
  if (half == 0) {
    unsigned sv = *(const unsigned*)(xrs + (size_t)node * NOUT + NREL * F + sl * 4);
    f32x2 lo = __builtin_amdgcn_cvt_pk_f32_fp8(sv, false);
    f32x2 hi = __builtin_amdgcn_cvt_pk_f32_fp8(sv, true);
    a0 += lo[0]; a1 += lo[1]; a2 += hi[0]; a3 += hi[1];
  }

  for (int base = beg; base < end; base += 64) {
    int cnt = end - base; if (cnt > 64) cnt = 64;
    int my = (base + lane < end) ? edata[base + lane] : 0;
    int pairs = cnt >> 1;
    int p = 0;
    for (; p + 8 <= pairs; p += 8) {
      unsigned v[8];
#pragma unroll
      for (int k = 0; k < 8; ++k) {
        int off = __shfl(my, 2 * (p + k) + half, 64);
        v[k] = *(const unsigned*)(xrs + (size_t)off + sl * 4);
      }
#pragma unroll
      for (int k = 0; k < 8; ++k) {
        f32x2 lo = __builtin_amdgcn_cvt_pk_f32_fp8(v[k], false);
        f32x2 hi = __builtin_amdgcn_cvt_pk_f32_fp8(v[k], true);
        a0 += lo[0]; a1 += lo[1]; a2 += hi[0]; a3 += hi[1];
      }
    }
    for (; p < pairs; ++p) {
      int off = __shfl(my, 2 * p + half, 64);
      unsigned vv = *(const unsigned*)(xrs + (size_t)off + sl * 4);
      f32x2 lo = __builtin_amdgcn_cvt_pk_f32_fp8(vv, false);
      f32x2 hi = __builtin_amdgcn_cvt_pk_f32_fp8(vv, true);
      a0 += lo[0]; a1 += lo[1]; a2 += hi[0]; a3 += hi[1];
    }
    if (cnt & 1) {
      int off = __shfl(my, cnt - 1, 64);
      if (half == 0) {
        unsigned vv = *(const unsigned*)(xrs + (size_t)off + sl * 4);
        f32x2 lo = __builtin_amdgcn_cvt_pk_f32_fp8(vv, false);
        f32x2 hi = __builtin_amdgcn_cvt_pk_f32_fp8(vv, true);
        a0 += lo[0]; a1 += lo[1]; a2 += hi[0]; a3 += hi[1];
      }
    }
  }

  // merge the two half-wave partial sums
  a0 += __shfl_xor(a0, 32, 64);
  a1 += __shfl_xor(a1, 32, 64);
  a2 += __shfl_xor(a2, 32, 64);
  a3 += __shfl_xor(a3, 32, 64);

  float4 bb = ((const float4*)bias)[sl];
  a0 = fmaxf(a0 + bb.x, 0.f);
  a1 = fmaxf(a1 + bb.y, 0.f);
  a2 = fmaxf(a2 + bb.z, 0.f);
  a3 = fmaxf(a3 + bb.w, 0.f);

  if (hout) {
    if (half == 0) {
      uint2 pk;
      pk.x = f2bf(a0) | (f2bf(a1) << 16);
      pk.y = f2bf(a2) | (f2bf(a3) << 16);
      ((uint2*)(hout + (size_t)node * F))[sl] = pk;
    }
  } else {
    if (half == 0) {
      red[wv][sl * 4 + 0] = a0;
      red[wv][sl * 4 + 1] = a1;
      red[wv][sl * 4 + 2] = a2;
      red[wv][sl * 4 + 3] = a3;
    }
    __syncthreads();
    if (threadIdx.x < 128) {
      float s = red[0][threadIdx.x] + red[1][threadIdx.x] +
                red[2][threadIdx.x] + red[3][threadIdx.x];
      atomicAdd(&pooled_p[(blockIdx.x & 63) * 128 + threadIdx.x], s);
    }
  }
}

// ================== final: reduce 64x128 partials + fc + sigmoid ============
__global__ __launch_bounds__(128)
void k_final(const float* __restrict__ pooled_p, const float* __restrict__ fcw,
             const float* __restrict__ fcb, float* __restrict__ out) {
  __shared__ float s[128];
  int t = threadIdx.x;
  float acc = 0.f;
#pragma unroll 8
  for (int k = 0; k < 64; ++k) acc += pooled_p[k * 128 + t];
  s[t] = acc * (1.0f / (float)NNODES) * fcw[t];
  __syncthreads();
  if (t == 0) {
    float v = 0.f;
    for (int i = 0; i < 128; ++i) v += s[i];
    v += fcb[0];
    out[0] = 1.f / (1.f + expf(-v));
  }
}

// ============================================================================
extern "C" void kernel_launch(void* const* d_in, const int* in_sizes, int n_in,
                              void* d_out, int out_size, void* d_ws, size_t ws_size,
                              hipStream_t stream) {
  const float* in_feat = (const float*)d_in[0];
  const float* W1      = (const float*)d_in[1];
  const float* W1s     = (const float*)d_in[2];
  const float* b1      = (const float*)d_in[3];
  const float* W2      = (const float*)d_in[4];
  const float* W2s     = (const float*)d_in[5];
  const float* b2      = (const float*)d_in[6];
  const float* fcw     = (const float*)d_in[7];
  const float* fcb     = (const float*)d_in[8];
  const int*   src     = (const int*)d_in[9];
  const int*   dst     = (const int*)d_in[10];
  const int*   et      = (const int*)d_in[11];
  float* out = (float*)d_out;

  // Workspace (~100 MB)
  unsigned char* xrs = (unsigned char*)d_ws;              // [50000][1152] fp8
  ushort* feat0 = (ushort*)(xrs + (size_t)NNODES * NOUT); // [50000][128] bf16
  ushort* h1    = feat0 + (size_t)NNODES * F;             // [50000][128]
  ushort* Wt1   = h1 + (size_t)NNODES * F;                // [1152][128]
  ushort* Wt2   = Wt1 + (size_t)NOUT * F;                 // [1152][128]
  float* pooled_p = (float*)(Wt2 + (size_t)NOUT * F);     // [64][128] } one
  int*   bcnt   = (int*)(pooled_p + 64 * 128);            // [NBKT]    } memset
  int*   rowptr = bcnt + NBKT;                            // [NNODES+1]
  int*   bbase  = rowptr + NNODES + 2;                    // [NBKT]
  int*   bcur   = bbase + NBKT;                           // [NBKT]
  int*   ebuf   = bcur + NBKT + 1;                        // [NEDGES]
  int*   edata  = ebuf + NEDGES;                          // [NEDGES]

  // single memset: pooled_p + bcnt
  hipMemsetAsync(pooled_p, 0, (64 * 128 + NBKT) * sizeof(float), stream);

  // fused prep: coarse hist | feat cvt | weight prep x2
  k_prep<<<PREP_CHIST + PREP_CVT + 2 * PREP_W, 256, 0, stream>>>(
      dst, bcnt, in_feat, feat0, W1, W1s, Wt1, W2, W2s, Wt2);
  k_cscan<<<1, 128, 0, stream>>>(bcnt, bbase, bcur, rowptr);

  const int aggBlocks = NNODES / 4;                    // 12500

  // Layer 1 GEMM with CSR-scatter fused (scatter hidden under GEMM)
  gemm_xrs<<<CSR_BLOCKS + GEMM_BLOCKS, 256, 0, stream>>>(
      feat0, Wt1, xrs, 1, src, dst, et, bcur, ebuf);
  k_fsort<<<NBKT, 256, 0, stream>>>(ebuf, bbase, bcnt, rowptr, edata);
  k_aggregate<<<aggBlocks, 256, 0, stream>>>(xrs, rowptr, edata, b1, h1, nullptr);
  // Layer 2 (pooling fused into aggregate; h2 never materialized)
  gemm_xrs<<<GEMM_BLOCKS, 256, 0, stream>>>(
      h1, Wt2, xrs, 0, src, dst, et, bcur, ebuf);
  k_aggregate<<<aggBlocks, 256, 0, stream>>>(xrs, rowptr, edata, b2, nullptr, pooled_p);

  // Reduce partials + fc + sigmoid
  k_final<<<1, 128, 0, stream>>>(pooled_p, fcw, fcb, out);
}

// Round 2
// 239.001 us; speedup vs baseline: 1.1763x; 1.1763x over previous
//
#include <hip/hip_runtime.h>

#define NNODES 50000
#define NEDGES 800000
#define F 128
#define NREL 8
#define NOUT 1152   // 9*128: 8 relations + self-loop
#define NBKT 98     // ceil(50000 / 512) coarse buckets
#define BSH 9       // 512 nodes per bucket
#define NTILES 391  // ceil(50000/128)
#define GEMM_BLOCKS (8 * 9 * 49)   // 3528 (XCD-swizzled)
#define CSR_BLOCKS 196

typedef short bf16x8 __attribute__((ext_vector_type(8)));
typedef float f32x4 __attribute__((ext_vector_type(4)));
typedef float f32x2 __attribute__((ext_vector_type(2)));

__device__ __forceinline__ unsigned f2bf(float f) {  // RNE
  unsigned u = __float_as_uint(f);
  u += 0x7fffu + ((u >> 16) & 1u);
  return u >> 16;
}
__device__ __forceinline__ float bf2f(unsigned v) {
  return __uint_as_float(v << 16);
}

// ========== fused prep: chist | cvt | prepw(W1) | prepw(W2) =================
#define PREP_CHIST 196
#define PREP_CVT   12500   // 50000*128/2 / 256
#define PREP_W     576     // 1152*128 / 256
__global__ __launch_bounds__(256)
void k_prep(const int* __restrict__ dst, int* __restrict__ bcnt,
            const float* __restrict__ in_feat, ushort* __restrict__ feat0,
            const float* __restrict__ W1, const float* __restrict__ W1s,
            ushort* __restrict__ Wt1,
            const float* __restrict__ W2, const float* __restrict__ W2s,
            ushort* __restrict__ Wt2) {
  const int b = blockIdx.x, t = threadIdx.x;
  if (b < PREP_CHIST) {
    __shared__ int hist[NBKT];
    if (t < NBKT) hist[t] = 0;
    __syncthreads();
    int e0 = b * 4096;
#pragma unroll
    for (int i = 0; i < 16; ++i) {
      int e = e0 + t + i * 256;
      if (e < NEDGES) atomicAdd(&hist[dst[e] >> BSH], 1);
    }
    __syncthreads();
    if (t < NBKT && hist[t] > 0) atomicAdd(&bcnt[t], hist[t]);
  } else if (b < PREP_CHIST + PREP_CVT) {
    int i = (b - PREP_CHIST) * 256 + t;  // exactly 3.2M
    float2 v = ((const float2*)in_feat)[i];
    ((unsigned*)feat0)[i] = f2bf(v.x) | (f2bf(v.y) << 16);
  } else {
    int w2 = (b >= PREP_CHIST + PREP_CVT + PREP_W);
    int idx = (b - PREP_CHIST - PREP_CVT - (w2 ? PREP_W : 0)) * 256 + t;
    int n = idx >> 7, k = idx & 127;
    int r = n >> 7, c = n & 127;
    const float* Wr = w2 ? W2 : W1;
    const float* Ws = w2 ? W2s : W1s;
    float v = (r < NREL) ? Wr[((size_t)r * F + k) * F + c] : Ws[(size_t)k * F + c];
    (w2 ? Wt2 : Wt1)[idx] = (ushort)f2bf(v);
  }
}

// ================= CSR scan =================================================
__global__ __launch_bounds__(128)
void k_cscan(const int* __restrict__ bcnt, int* __restrict__ bbase,
             int* __restrict__ bcur, int* __restrict__ rowptr) {
  __shared__ int s[128];
  int t = threadIdx.x;
  int v = (t < NBKT) ? bcnt[t] : 0;
  s[t] = v;
  __syncthreads();
  for (int off = 1; off < 128; off <<= 1) {
    int x = (t >= off) ? s[t - off] : 0;
    __syncthreads();
    s[t] += x;
    __syncthreads();
  }
  if (t < NBKT) { bbase[t] = s[t] - v; bcur[t] = s[t] - v; }
  if (t == 0) rowptr[NNODES] = NEDGES;
}

__global__ __launch_bounds__(256)
void k_fsort(const int* __restrict__ ebuf, const int* __restrict__ bbase,
             const int* __restrict__ bcnt, int* __restrict__ rowptr,
             int* __restrict__ edata) {
  __shared__ int cnt[512];
  __shared__ int pos[512];
  __shared__ int ws2[256];
  const int b = blockIdx.x, t = threadIdx.x;
  const int beg = bbase[b], end = beg + bcnt[b];
  cnt[t] = 0; cnt[t + 256] = 0;
  __syncthreads();
  for (int e = beg + t; e < end; e += 256)
    atomicAdd(&cnt[((unsigned)ebuf[e]) >> 19], 1);
  __syncthreads();
  int a = cnt[2 * t], b2 = cnt[2 * t + 1];
  ws2[t] = a + b2;
  __syncthreads();
  for (int off = 1; off < 256; off <<= 1) {
    int x = (t >= off) ? ws2[t - off] : 0;
    __syncthreads();
    ws2[t] += x;
    __syncthreads();
  }
  int ep = ws2[t] - (a + b2);
  pos[2 * t] = ep;
  pos[2 * t + 1] = ep + a;
  __syncthreads();
  int node0 = b << BSH;
#pragma unroll
  for (int i = t; i < 512; i += 256) {
    int node = node0 + i;
    if (node < NNODES) rowptr[node] = beg + pos[i];
  }
  __syncthreads();
  for (int e = beg + t; e < end; e += 256) {
    int rec = ebuf[e];
    int c = ((unsigned)rec) >> 19;
    int lrank = atomicAdd(&pos[c], 1);
    int srcv = (rec >> 3) & 0xFFFF;
    int etv = rec & 7;
    edata[beg + lrank] = srcv * NOUT + etv * F;  // byte offset in fp8 xrs
  }
}

// ====== GEMM: xrs[50000][1152](fp8) = A[50000][128] @ Wt^T  (bf16 MFMA) =====
// R14 structure (proven 53us): full-K, one barrier, XOR-swizzled 64KB LDS,
// 512 threads / 8 waves (32x64 each). Bit-identical results.
// R16 change: epilogue LDS-transpose. Old: 8 scattered dword stores/lane
// (16x16B segments per wave-instr -> 3.6M L2 write requests). New: pack fp8
// dwords into a swizzled 16KB staging buffer (aliased onto As), barrier,
// cooperative dwordx4 stores where 8 lanes cover one node's contiguous 128B
// slice (8x128B segments per instr, 8x fewer requests). Bytes identical.
// doCsr: blocks [0,196) instead run the coarse CSR scatter.
__global__ __launch_bounds__(512, 4)
void gemm_xrs(const ushort* __restrict__ A, const ushort* __restrict__ Wt,
              unsigned char* __restrict__ xrs, int doCsr,
              const int* __restrict__ src, const int* __restrict__ dst,
              const int* __restrict__ et, int* __restrict__ bcur,
              int* __restrict__ ebuf) {
  __shared__ uint4 As[2048];  // 128 rows x 16 uint4, xor-swizzled
  __shared__ uint4 Bs[2048];
  __shared__ int lhist[NBKT];
  __shared__ int lbase[NBKT];
  const int tid = threadIdx.x;

  if (doCsr && blockIdx.x < CSR_BLOCKS) {
    // ---- coarse scatter: record = (dst_local<<19)|(src<<3)|et ----
    if (tid < NBKT) lhist[tid] = 0;
    __syncthreads();
    int e0 = blockIdx.x * 4096;
    int rec[8], cc[8], lr[8];
#pragma unroll
    for (int i = 0; i < 8; ++i) {
      int e = e0 + tid + i * 512;
      if (e < NEDGES) {
        int d = dst[e];
        cc[i] = d >> BSH;
        rec[i] = ((d & 511) << 19) | (src[e] << 3) | et[e];
        lr[i] = atomicAdd(&lhist[cc[i]], 1);
      } else {
        cc[i] = -1;
      }
    }
    __syncthreads();
    if (tid < NBKT && lhist[tid] > 0) lbase[tid] = atomicAdd(&bcur[tid], lhist[tid]);
    __syncthreads();
#pragma unroll
    for (int i = 0; i < 8; ++i)
      if (cc[i] >= 0) ebuf[lbase[cc[i]] + lr[i]] = rec[i];
    return;
  }

  const int id = blockIdx.x - (doCsr ? CSR_BLOCKS : 0);
  const int x = id & 7, j = id >> 3;
  const int tile = (j / 9) * 8 + x;
  const int cb = j % 9;
  if (tile >= NTILES) return;
  const int row0 = tile * 128;

  const int lane = tid & 63;
  const int w = tid >> 6;           // 0..7
  const int i16 = lane & 15, q = lane >> 4;
  const int mbase = (w & 3) * 32, nbase = (w >> 2) * 64;

  // Stage full tiles: 2048 uint4 slots each, 4 per thread.
  uint4 va[4], vb[4];
#pragma unroll
  for (int i = 0; i < 4; ++i) {
    int L = tid + i * 512;
    int r = L >> 4, c4 = L & 15;
    int agr = row0 + r; if (agr >= NNODES) agr = NNODES - 1;
    va[i] = *(const uint4*)(A + (size_t)agr * F + c4 * 8);
    vb[i] = *(const uint4*)(Wt + ((size_t)cb * 128 + r) * F + c4 * 8);
  }
#pragma unroll
  for (int i = 0; i < 4; ++i) {
    int L = tid + i * 512;
    int r = L >> 4, c4 = L & 15;
    int sidx = r * 16 + (c4 ^ (r & 15));
    As[sidx] = va[i];
    Bs[sidx] = vb[i];
  }
  __syncthreads();

  f32x4 acc[2][4];
#pragma unroll
  for (int a = 0; a < 2; ++a)
#pragma unroll
    for (int b = 0; b < 4; ++b) acc[a][b] = (f32x4)0.f;

#pragma unroll
  for (int c = 0; c < 4; ++c) {
    bf16x8 af[2], bfr[4];
#pragma unroll
    for (int mi = 0; mi < 2; ++mi) {
      int r = mbase + mi * 16 + i16;
      af[mi] = *(const bf16x8*)&As[r * 16 + ((c * 4 + q) ^ (r & 15))];
    }
#pragma unroll
    for (int ni = 0; ni < 4; ++ni) {
      int r = nbase + ni * 16 + i16;
      bfr[ni] = *(const bf16x8*)&Bs[r * 16 + ((c * 4 + q) ^ (r & 15))];
    }
    // Swapped operands: D[m=weight feature][n=node row]
#pragma unroll
    for (int mi = 0; mi < 2; ++mi)
#pragma unroll
      for (int ni = 0; ni < 4; ++ni)
        acc[mi][ni] = __builtin_amdgcn_mfma_f32_16x16x32_bf16(
            bfr[ni], af[mi], acc[mi][ni], 0, 0, 0);
  }

  // ---- Epilogue with LDS transpose (R16) ----
  // Lane holds node nl = mbase+mi*16+i16 (local 0..127), feature dwords
  // d = nbase/4 + ni*4 + q (feats 4d..4d+3). Pack fp8 dwords (bit-identical
  // to R14's direct stores), stage into swizzled sbuf[nl][32], then store
  // cooperatively: 8 lanes x 16B = one node's contiguous 128B slice.
  unsigned pkv[2][4];
#pragma unroll
  for (int mi = 0; mi < 2; ++mi)
#pragma unroll
    for (int ni = 0; ni < 4; ++ni) {
      f32x4 v = acc[mi][ni];
      unsigned pk = 0;
      pk = __builtin_amdgcn_cvt_pk_fp8_f32(v[0], v[1], pk, false);
      pk = __builtin_amdgcn_cvt_pk_fp8_f32(v[2], v[3], pk, true);
      pkv[mi][ni] = pk;
    }

  __syncthreads();  // all waves done reading As/Bs; reuse As as staging
  unsigned* sbuf = (unsigned*)As;  // [128 nodes][32 dwords] = 16KB
  {
    const int dbase = (nbase >> 2) + q;
#pragma unroll
    for (int mi = 0; mi < 2; ++mi) {
      int nl = mbase + mi * 16 + i16;
      int sw = (nl & 7) << 2;
      int vb_ = nl * 32;
#pragma unroll
      for (int ni = 0; ni < 4; ++ni)
        sbuf[vb_ + ((dbase + ni * 4) ^ sw)] = pkv[mi][ni];
    }
  }
  __syncthreads();

#pragma unroll
  for (int k = 0; k < 2; ++k) {
    int nl = k * 64 + (tid >> 3);
    int ch = tid & 7;
    int d0 = (ch * 4) ^ ((nl & 7) << 2);
    uint4 v = *(const uint4*)&sbuf[nl * 32 + d0];
    int row = row0 + nl;
    if (row < NNODES)
      *(uint4*)(xrs + (size_t)row * NOUT + cb * 128 + ch * 16) = v;
  }
}

// ========== aggregate: h_next[dst] = relu(sum_e xrs[edata] + self + b) ======
// Paired-edge: half-wave (32 lanes) per edge, 4B dword loads (full 128B row
// per half-wave), 8 pairs (16 edges) in flight, __shfl for offsets,
// __shfl_xor(32) merges halves. 12500 blocks x 4 nodes = 50000 exactly.
// hout != null: store bf16 h. pooled_p != null: LDS-reduce block's 4 nodes,
// atomicAdd into 64-slot-spread partials (pooling fused; h2 never written).
__global__ __launch_bounds__(256)
void k_aggregate(const unsigned char* __restrict__ xrs,
                 const int* __restrict__ rowptr, const int* __restrict__ edata,
                 const float* __restrict__ bias, ushort* __restrict__ hout,
                 float* __restrict__ pooled_p) {
  __shared__ float red[4][128];
  const int wv = threadIdx.x >> 6;
  const int node = blockIdx.x * 4 + wv;
  const int lane = threadIdx.x & 63;
  const int half = lane >> 5, sl = lane & 31;
  const int beg = rowptr[node], end = rowptr[node + 1];

  float a0 = 0.f, a1 = 0.f, a2 = 0.f, a3 = 0.f;
  // self-loop row (r=8), counted once by half 0
  if (half == 0) {
    unsigned sv = *(const unsigned*)(xrs + (size_t)node * NOUT + NREL * F + sl * 4);
    f32x2 lo = __builtin_amdgcn_cvt_pk_f32_fp8(sv, false);
    f32x2 hi = __builtin_amdgcn_cvt_pk_f32_fp8(sv, true);
    a0 += lo[0]; a1 += lo[1]; a2 += hi[0]; a3 += hi[1];
  }

  for (int base = beg; base < end; base += 64) {
    int cnt = end - base; if (cnt > 64) cnt = 64;
    int my = (base + lane < end) ? edata[base + lane] : 0;
    int pairs = cnt >> 1;
    int p = 0;
    for (; p + 8 <= pairs; p += 8) {
      unsigned v[8];
#pragma unroll
      for (int k = 0; k < 8; ++k) {
        int off = __shfl(my, 2 * (p + k) + half, 64);
        v[k] = *(const unsigned*)(xrs + (size_t)off + sl * 4);
      }
#pragma unroll
      for (int k = 0; k < 8; ++k) {
        f32x2 lo = __builtin_amdgcn_cvt_pk_f32_fp8(v[k], false);
        f32x2 hi = __builtin_amdgcn_cvt_pk_f32_fp8(v[k], true);
        a0 += lo[0]; a1 += lo[1]; a2 += hi[0]; a3 += hi[1];
      }
    }
    for (; p < pairs; ++p) {
      int off = __shfl(my, 2 * p + half, 64);
      unsigned vv = *(const unsigned*)(xrs + (size_t)off + sl * 4);
      f32x2 lo = __builtin_amdgcn_cvt_pk_f32_fp8(vv, false);
      f32x2 hi = __builtin_amdgcn_cvt_pk_f32_fp8(vv, true);
      a0 += lo[0]; a1 += lo[1]; a2 += hi[0]; a3 += hi[1];
    }
    if (cnt & 1) {
      int off = __shfl(my, cnt - 1, 64);
      if (half == 0) {
        unsigned vv = *(const unsigned*)(xrs + (size_t)off + sl * 4);
        f32x2 lo = __builtin_amdgcn_cvt_pk_f32_fp8(vv, false);
        f32x2 hi = __builtin_amdgcn_cvt_pk_f32_fp8(vv, true);
        a0 += lo[0]; a1 += lo[1]; a2 += hi[0]; a3 += hi[1];
      }
    }
  }

  // merge the two half-wave partial sums
  a0 += __shfl_xor(a0, 32, 64);
  a1 += __shfl_xor(a1, 32, 64);
  a2 += __shfl_xor(a2, 32, 64);
  a3 += __shfl_xor(a3, 32, 64);

  float4 bb = ((const float4*)bias)[sl];
  a0 = fmaxf(a0 + bb.x, 0.f);
  a1 = fmaxf(a1 + bb.y, 0.f);
  a2 = fmaxf(a2 + bb.z, 0.f);
  a3 = fmaxf(a3 + bb.w, 0.f);

  if (hout) {
    if (half == 0) {
      uint2 pk;
      pk.x = f2bf(a0) | (f2bf(a1) << 16);
      pk.y = f2bf(a2) | (f2bf(a3) << 16);
      ((uint2*)(hout + (size_t)node * F))[sl] = pk;
    }
  } else {
    if (half == 0) {
      red[wv][sl * 4 + 0] = a0;
      red[wv][sl * 4 + 1] = a1;
      red[wv][sl * 4 + 2] = a2;
      red[wv][sl * 4 + 3] = a3;
    }
    __syncthreads();
    if (threadIdx.x < 128) {
      float s = red[0][threadIdx.x] + red[1][threadIdx.x] +
                red[2][threadIdx.x] + red[3][threadIdx.x];
      atomicAdd(&pooled_p[(blockIdx.x & 63) * 128 + threadIdx.x], s);
    }
  }
}

// ================== final: reduce 64x128 partials + fc + sigmoid ============
__global__ __launch_bounds__(128)
void k_final(const float* __restrict__ pooled_p, const float* __restrict__ fcw,
             const float* __restrict__ fcb, float* __restrict__ out) {
  __shared__ float s[128];
  int t = threadIdx.x;
  float acc = 0.f;
#pragma unroll 8
  for (int k = 0; k < 64; ++k) acc += pooled_p[k * 128 + t];
  s[t] = acc * (1.0f / (float)NNODES) * fcw[t];
  __syncthreads();
  if (t == 0) {
    float v = 0.f;
    for (int i = 0; i < 128; ++i) v += s[i];
    v += fcb[0];
    out[0] = 1.f / (1.f + expf(-v));
  }
}

// ============================================================================
extern "C" void kernel_launch(void* const* d_in, const int* in_sizes, int n_in,
                              void* d_out, int out_size, void* d_ws, size_t ws_size,
                              hipStream_t stream) {
  const float* in_feat = (const float*)d_in[0];
  const float* W1      = (const float*)d_in[1];
  const float* W1s     = (const float*)d_in[2];
  const float* b1      = (const float*)d_in[3];
  const float* W2      = (const float*)d_in[4];
  const float* W2s     = (const float*)d_in[5];
  const float* b2      = (const float*)d_in[6];
  const float* fcw     = (const float*)d_in[7];
  const float* fcb     = (const float*)d_in[8];
  const int*   src     = (const int*)d_in[9];
  const int*   dst     = (const int*)d_in[10];
  const int*   et      = (const int*)d_in[11];
  float* out = (float*)d_out;

  // Workspace (~100 MB)
  unsigned char* xrs = (unsigned char*)d_ws;              // [50000][1152] fp8
  ushort* feat0 = (ushort*)(xrs + (size_t)NNODES * NOUT); // [50000][128] bf16
  ushort* h1    = feat0 + (size_t)NNODES * F;             // [50000][128]
  ushort* Wt1   = h1 + (size_t)NNODES * F;                // [1152][128]
  ushort* Wt2   = Wt1 + (size_t)NOUT * F;                 // [1152][128]
  float* pooled_p = (float*)(Wt2 + (size_t)NOUT * F);     // [64][128] } one
  int*   bcnt   = (int*)(pooled_p + 64 * 128);            // [NBKT]    } memset
  int*   rowptr = bcnt + NBKT;                            // [NNODES+1]
  int*   bbase  = rowptr + NNODES + 2;                    // [NBKT]
  int*   bcur   = bbase + NBKT;                           // [NBKT]
  int*   ebuf   = bcur + NBKT + 1;                        // [NEDGES]
  int*   edata  = ebuf + NEDGES;                          // [NEDGES]

  // single memset: pooled_p + bcnt
  hipMemsetAsync(pooled_p, 0, (64 * 128 + NBKT) * sizeof(float), stream);

  // fused prep: coarse hist | feat cvt | weight prep x2
  k_prep<<<PREP_CHIST + PREP_CVT + 2 * PREP_W, 256, 0, stream>>>(
      dst, bcnt, in_feat, feat0, W1, W1s, Wt1, W2, W2s, Wt2);
  k_cscan<<<1, 128, 0, stream>>>(bcnt, bbase, bcur, rowptr);

  const int aggBlocks = NNODES / 4;                    // 12500

  // Layer 1 GEMM with CSR-scatter fused (scatter hidden under GEMM)
  gemm_xrs<<<CSR_BLOCKS + GEMM_BLOCKS, 512, 0, stream>>>(
      feat0, Wt1, xrs, 1, src, dst, et, bcur, ebuf);
  k_fsort<<<NBKT, 256, 0, stream>>>(ebuf, bbase, bcnt, rowptr, edata);
  k_aggregate<<<aggBlocks, 256, 0, stream>>>(xrs, rowptr, edata, b1, h1, nullptr);
  // Layer 2 (pooling fused into aggregate; h2 never materialized)
  gemm_xrs<<<GEMM_BLOCKS, 512, 0, stream>>>(
      h1, Wt2, xrs, 0, src, dst, et, bcur, ebuf);
  k_aggregate<<<aggBlocks, 256, 0, stream>>>(xrs, rowptr, edata, b2, nullptr, pooled_p);

  // Reduce partials + fc + sigmoid
  k_final<<<1, 128, 0, stream>>>(pooled_p, fcw, fcb, out);
}

// Round 3
// 232.583 us; speedup vs baseline: 1.2088x; 1.0276x over previous
//
#include <hip/hip_runtime.h>

#define NNODES 50000
#define NEDGES 800000
#define F 128
#define NREL 8
#define NOUT 1152   // 9*128: 8 relations + self-loop
#define NBKT 98     // ceil(50000 / 512) coarse buckets
#define BSH 9       // 512 nodes per bucket
#define SEG 16384   // fixed ebuf segment per bucket (max bucket ~8.5k)
#define NTILES 391  // ceil(50000/128)
#define GEMM_BLOCKS (8 * 9 * 49)   // 3528 (XCD-swizzled)
#define CSR_BLOCKS 196

typedef short bf16x8 __attribute__((ext_vector_type(8)));
typedef float f32x4 __attribute__((ext_vector_type(4)));
typedef float f32x2 __attribute__((ext_vector_type(2)));

__device__ __forceinline__ unsigned f2bf(float f) {  // RNE
  unsigned u = __float_as_uint(f);
  u += 0x7fffu + ((u >> 16) & 1u);
  return u >> 16;
}
__device__ __forceinline__ float bf2f(unsigned v) {
  return __uint_as_float(v << 16);
}

typedef __attribute__((address_space(3))) void lds_void;
typedef const __attribute__((address_space(1))) void glb_void;
__device__ __forceinline__ void gll16(const void* g, void* l) {
  // async global->LDS, 16B per lane; LDS dest = wave-uniform base + lane*16
  __builtin_amdgcn_global_load_lds(
      (glb_void*)(unsigned long long)g,
      (lds_void*)(unsigned)(unsigned long long)l, 16, 0, 0);
}

// ========== fused prep: chist | cvt | prepw(W1) | prepw(W2) =================
#define PREP_CHIST 196
#define PREP_CVT   12500   // 50000*128/2 / 256
#define PREP_W     576     // 1152*128 / 256
__global__ __launch_bounds__(256)
void k_prep(const int* __restrict__ dst, int* __restrict__ bcnt,
            const float* __restrict__ in_feat, ushort* __restrict__ feat0,
            const float* __restrict__ W1, const float* __restrict__ W1s,
            ushort* __restrict__ Wt1,
            const float* __restrict__ W2, const float* __restrict__ W2s,
            ushort* __restrict__ Wt2) {
  const int b = blockIdx.x, t = threadIdx.x;
  if (b < PREP_CHIST) {
    __shared__ int hist[NBKT];
    if (t < NBKT) hist[t] = 0;
    __syncthreads();
    int e0 = b * 4096;
#pragma unroll
    for (int i = 0; i < 16; ++i) {
      int e = e0 + t + i * 256;
      if (e < NEDGES) atomicAdd(&hist[dst[e] >> BSH], 1);
    }
    __syncthreads();
    if (t < NBKT && hist[t] > 0) atomicAdd(&bcnt[t], hist[t]);
  } else if (b < PREP_CHIST + PREP_CVT) {
    int i = (b - PREP_CHIST) * 256 + t;  // exactly 3.2M
    float2 v = ((const float2*)in_feat)[i];
    ((unsigned*)feat0)[i] = f2bf(v.x) | (f2bf(v.y) << 16);
  } else {
    int w2 = (b >= PREP_CHIST + PREP_CVT + PREP_W);
    int idx = (b - PREP_CHIST - PREP_CVT - (w2 ? PREP_W : 0)) * 256 + t;
    int n = idx >> 7, k = idx & 127;
    int r = n >> 7, c = n & 127;
    const float* Wr = w2 ? W2 : W1;
    const float* Ws = w2 ? W2s : W1s;
    float v = (r < NREL) ? Wr[((size_t)r * F + k) * F + c] : Ws[(size_t)k * F + c];
    (w2 ? Wt2 : Wt1)[idx] = (ushort)f2bf(v);
  }
}

// ======== fine sort: bucket segment -> CSR (computes own global base) =======
__global__ __launch_bounds__(256)
void k_fsort(const int* __restrict__ ebuf, const int* __restrict__ bcnt,
             int* __restrict__ rowptr, int* __restrict__ edata) {
  __shared__ int cnt[512];
  __shared__ int pos[512];
  __shared__ int ws2[256];
  const int b = blockIdx.x, t = threadIdx.x;
  // ---- global base = sum_{k<b} bcnt[k] (98-wide scan, replaces k_cscan) ----
  int myc = (t < NBKT) ? bcnt[t] : 0;
  ws2[t] = (t < b) ? myc : 0;
  __syncthreads();
  for (int off = 1; off < 256; off <<= 1) {
    int x = (t >= off) ? ws2[t - off] : 0;
    __syncthreads();
    ws2[t] += x;
    __syncthreads();
  }
  const int beg = ws2[255];
  const int mycnt = (t == b) ? myc : 0;
  __syncthreads();
  const int end = beg + __shfl(myc, b & 63, 64);  // bcnt[b] via lane b (b<98)
  // NOTE: b can be >=64; use LDS broadcast instead for safety:
  __shared__ int bc_s;
  if (t == b) bc_s = myc;
  __syncthreads();
  const int cntb = bc_s;
  const int sbeg = b * SEG;  // segment start in ebuf
  (void)mycnt; (void)end;

  cnt[t] = 0; cnt[t + 256] = 0;
  __syncthreads();
  for (int e = t; e < cntb; e += 256)
    atomicAdd(&cnt[((unsigned)ebuf[sbeg + e]) >> 19], 1);
  __syncthreads();
  int a = cnt[2 * t], b2 = cnt[2 * t + 1];
  ws2[t] = a + b2;
  __syncthreads();
  for (int off = 1; off < 256; off <<= 1) {
    int x = (t >= off) ? ws2[t - off] : 0;
    __syncthreads();
    ws2[t] += x;
    __syncthreads();
  }
  int ep = ws2[t] - (a + b2);
  pos[2 * t] = ep;
  pos[2 * t + 1] = ep + a;
  __syncthreads();
  int node0 = b << BSH;
#pragma unroll
  for (int i = t; i < 512; i += 256) {
    int node = node0 + i;
    if (node < NNODES) rowptr[node] = beg + pos[i];
  }
  if (b == NBKT - 1 && t == 0) rowptr[NNODES] = NEDGES;
  __syncthreads();
  for (int e = t; e < cntb; e += 256) {
    int rec = ebuf[sbeg + e];
    int c = ((unsigned)rec) >> 19;
    int lrank = atomicAdd(&pos[c], 1);
    int srcv = (rec >> 3) & 0xFFFF;
    int etv = rec & 7;
    edata[beg + lrank] = srcv * NOUT + etv * F;  // byte offset in fp8 xrs
  }
}

// ====== GEMM: xrs[50000][1152](fp8) = A[50000][128] @ Wt^T  (bf16 MFMA) =====
// R14 structure (proven): full-K, one barrier, XOR-swizzled 64KB LDS,
// 512 threads / 8 waves (32x64 each). R16: epilogue LDS-transpose stores
// (8x128B segments per wave-instr). R17: staging via global_load_lds
// (linear LDS dest + pre-swizzled source, rule 21) - no VGPR round-trip.
// doCsr: blocks [0,196) instead run the coarse CSR scatter (fixed-stride
// segments, bucket-local counters; no prefix scan needed before this).
__global__ __launch_bounds__(512, 4)
void gemm_xrs(const ushort* __restrict__ A, const ushort* __restrict__ Wt,
              unsigned char* __restrict__ xrs, int doCsr,
              const int* __restrict__ src, const int* __restrict__ dst,
              const int* __restrict__ et, int* __restrict__ bcur,
              int* __restrict__ ebuf) {
  __shared__ uint4 As[2048];  // 128 rows x 16 uint4, xor-swizzled
  __shared__ uint4 Bs[2048];
  __shared__ int lhist[NBKT];
  __shared__ int lbase[NBKT];
  const int tid = threadIdx.x;

  if (doCsr && blockIdx.x < CSR_BLOCKS) {
    // ---- coarse scatter: record = (dst_local<<19)|(src<<3)|et ----
    if (tid < NBKT) lhist[tid] = 0;
    __syncthreads();
    int e0 = blockIdx.x * 4096;
    int rec[8], cc[8], lr[8];
#pragma unroll
    for (int i = 0; i < 8; ++i) {
      int e = e0 + tid + i * 512;
      if (e < NEDGES) {
        int d = dst[e];
        cc[i] = d >> BSH;
        rec[i] = ((d & 511) << 19) | (src[e] << 3) | et[e];
        lr[i] = atomicAdd(&lhist[cc[i]], 1);
      } else {
        cc[i] = -1;
      }
    }
    __syncthreads();
    if (tid < NBKT && lhist[tid] > 0) lbase[tid] = atomicAdd(&bcur[tid], lhist[tid]);
    __syncthreads();
#pragma unroll
    for (int i = 0; i < 8; ++i)
      if (cc[i] >= 0) ebuf[cc[i] * SEG + lbase[cc[i]] + lr[i]] = rec[i];
    return;
  }

  const int id = blockIdx.x - (doCsr ? CSR_BLOCKS : 0);
  const int x = id & 7, j = id >> 3;
  const int tile = (j / 9) * 8 + x;
  const int cb = j % 9;
  if (tile >= NTILES) return;
  const int row0 = tile * 128;

  const int lane = tid & 63;
  const int w = tid >> 6;           // 0..7
  const int i16 = lane & 15, q = lane >> 4;
  const int mbase = (w & 3) * 32, nbase = (w >> 2) * 64;

  // Stage full tiles via global_load_lds: linear LDS dest slot L receives
  // source column (L&15) ^ (r&15)  (same XOR involution as the read side).
#pragma unroll
  for (int i = 0; i < 4; ++i) {
    int L = tid + i * 512;
    int r = L >> 4, c4s = L & 15;
    int c4 = c4s ^ (r & 15);
    int agr = row0 + r; if (agr >= NNODES) agr = NNODES - 1;
    gll16((const void*)(A + (size_t)agr * F + c4 * 8), (void*)&As[L]);
    gll16((const void*)(Wt + ((size_t)cb * 128 + r) * F + c4 * 8), (void*)&Bs[L]);
  }
  __syncthreads();

  f32x4 acc[2][4];
#pragma unroll
  for (int a = 0; a < 2; ++a)
#pragma unroll
    for (int b = 0; b < 4; ++b) acc[a][b] = (f32x4)0.f;

#pragma unroll
  for (int c = 0; c < 4; ++c) {
    bf16x8 af[2], bfr[4];
#pragma unroll
    for (int mi = 0; mi < 2; ++mi) {
      int r = mbase + mi * 16 + i16;
      af[mi] = *(const bf16x8*)&As[r * 16 + ((c * 4 + q) ^ (r & 15))];
    }
#pragma unroll
    for (int ni = 0; ni < 4; ++ni) {
      int r = nbase + ni * 16 + i16;
      bfr[ni] = *(const bf16x8*)&Bs[r * 16 + ((c * 4 + q) ^ (r & 15))];
    }
    // Swapped operands: D[m=weight feature][n=node row]
#pragma unroll
    for (int mi = 0; mi < 2; ++mi)
#pragma unroll
      for (int ni = 0; ni < 4; ++ni)
        acc[mi][ni] = __builtin_amdgcn_mfma_f32_16x16x32_bf16(
            bfr[ni], af[mi], acc[mi][ni], 0, 0, 0);
  }

  // ---- Epilogue with LDS transpose (R16) ----
  // Lane holds node nl = mbase+mi*16+i16 (local 0..127), feature dwords
  // d = nbase/4 + ni*4 + q (feats 4d..4d+3). Pack fp8 dwords (bit-identical),
  // stage into swizzled sbuf[nl][32], then store cooperatively: 8 lanes x
  // 16B = one node's contiguous 128B slice.
  unsigned pkv[2][4];
#pragma unroll
  for (int mi = 0; mi < 2; ++mi)
#pragma unroll
    for (int ni = 0; ni < 4; ++ni) {
      f32x4 v = acc[mi][ni];
      unsigned pk = 0;
      pk = __builtin_amdgcn_cvt_pk_fp8_f32(v[0], v[1], pk, false);
      pk = __builtin_amdgcn_cvt_pk_fp8_f32(v[2], v[3], pk, true);
      pkv[mi][ni] = pk;
    }

  __syncthreads();  // all waves done reading As/Bs; reuse As as staging
  unsigned* sbuf = (unsigned*)As;  // [128 nodes][32 dwords] = 16KB
  {
    const int dbase = (nbase >> 2) + q;
#pragma unroll
    for (int mi = 0; mi < 2; ++mi) {
      int nl = mbase + mi * 16 + i16;
      int sw = (nl & 7) << 2;
      int vb_ = nl * 32;
#pragma unroll
      for (int ni = 0; ni < 4; ++ni)
        sbuf[vb_ + ((dbase + ni * 4) ^ sw)] = pkv[mi][ni];
    }
  }
  __syncthreads();

#pragma unroll
  for (int k = 0; k < 2; ++k) {
    int nl = k * 64 + (tid >> 3);
    int ch = tid & 7;
    int d0 = (ch * 4) ^ ((nl & 7) << 2);
    uint4 v = *(const uint4*)&sbuf[nl * 32 + d0];
    int row = row0 + nl;
    if (row < NNODES)
      *(uint4*)(xrs + (size_t)row * NOUT + cb * 128 + ch * 16) = v;
  }
}

// ========== aggregate: h_next[dst] = relu(sum_e xrs[edata] + self + b) ======
// Paired-edge: half-wave (32 lanes) per edge, 4B dword loads (full 128B row
// per half-wave), 8 pairs (16 edges) in flight, __shfl for offsets,
// __shfl_xor(32) merges halves. 12500 blocks x 4 nodes = 50000 exactly.
// hout != null: store bf16 h. pooled_p != null: LDS-reduce block's 4 nodes,
// atomicAdd into 64-slot-spread partials (pooling fused; h2 never written).
__global__ __launch_bounds__(256)
void k_aggregate(const unsigned char* __restrict__ xrs,
                 const int* __restrict__ rowptr, const int* __restrict__ edata,
                 const float* __restrict__ bias, ushort* __restrict__ hout,
                 float* __restrict__ pooled_p) {
  __shared__ float red[4][128];
  const int wv = threadIdx.x >> 6;
  const int node = blockIdx.x * 4 + wv;
  const int lane = threadIdx.x & 63;
  const int half = lane >> 5, sl = lane & 31;
  const int beg = rowptr[node], end = rowptr[node + 1];

  float a0 = 0.f, a1 = 0.f, a2 = 0.f, a3 = 0.f;
  // self-loop row (r=8), counted once by half 0
  if (half == 0) {
    unsigned sv = *(const unsigned*)(xrs + (size_t)node * NOUT + NREL * F + sl * 4);
    f32x2 lo = __builtin_amdgcn_cvt_pk_f32_fp8(sv, false);
    f32x2 hi = __builtin_amdgcn_cvt_pk_f32_fp8(sv, true);
    a0 += lo[0]; a1 += lo[1]; a2 += hi[0]; a3 += hi[1];
  }

  for (int base = beg; base < end; base += 64) {
    int cnt = end - base; if (cnt > 64) cnt = 64;
    int my = (base + lane < end) ? edata[base + lane] : 0;
    int pairs = cnt >> 1;
    int p = 0;
    for (; p + 8 <= pairs; p += 8) {
      unsigned v[8];
#pragma unroll
      for (int k = 0; k < 8; ++k) {
        int off = __shfl(my, 2 * (p + k) + half, 64);
        v[k] = *(const unsigned*)(xrs + (size_t)off + sl * 4);
      }
#pragma unroll
      for (int k = 0; k < 8; ++k) {
        f32x2 lo = __builtin_amdgcn_cvt_pk_f32_fp8(v[k], false);
        f32x2 hi = __builtin_amdgcn_cvt_pk_f32_fp8(v[k], true);
        a0 += lo[0]; a1 += lo[1]; a2 += hi[0]; a3 += hi[1];
      }
    }
    for (; p < pairs; ++p) {
      int off = __shfl(my, 2 * p + half, 64);
      unsigned vv = *(const unsigned*)(xrs + (size_t)off + sl * 4);
      f32x2 lo = __builtin_amdgcn_cvt_pk_f32_fp8(vv, false);
      f32x2 hi = __builtin_amdgcn_cvt_pk_f32_fp8(vv, true);
      a0 += lo[0]; a1 += lo[1]; a2 += hi[0]; a3 += hi[1];
    }
    if (cnt & 1) {
      int off = __shfl(my, cnt - 1, 64);
      if (half == 0) {
        unsigned vv = *(const unsigned*)(xrs + (size_t)off + sl * 4);
        f32x2 lo = __builtin_amdgcn_cvt_pk_f32_fp8(vv, false);
        f32x2 hi = __builtin_amdgcn_cvt_pk_f32_fp8(vv, true);
        a0 += lo[0]; a1 += lo[1]; a2 += hi[0]; a3 += hi[1];
      }
    }
  }

  // merge the two half-wave partial sums
  a0 += __shfl_xor(a0, 32, 64);
  a1 += __shfl_xor(a1, 32, 64);
  a2 += __shfl_xor(a2, 32, 64);
  a3 += __shfl_xor(a3, 32, 64);

  float4 bb = ((const float4*)bias)[sl];
  a0 = fmaxf(a0 + bb.x, 0.f);
  a1 = fmaxf(a1 + bb.y, 0.f);
  a2 = fmaxf(a2 + bb.z, 0.f);
  a3 = fmaxf(a3 + bb.w, 0.f);

  if (hout) {
    if (half == 0) {
      uint2 pk;
      pk.x = f2bf(a0) | (f2bf(a1) << 16);
      pk.y = f2bf(a2) | (f2bf(a3) << 16);
      ((uint2*)(hout + (size_t)node * F))[sl] = pk;
    }
  } else {
    if (half == 0) {
      red[wv][sl * 4 + 0] = a0;
      red[wv][sl * 4 + 1] = a1;
      red[wv][sl * 4 + 2] = a2;
      red[wv][sl * 4 + 3] = a3;
    }
    __syncthreads();
    if (threadIdx.x < 128) {
      float s = red[0][threadIdx.x] + red[1][threadIdx.x] +
                red[2][threadIdx.x] + red[3][threadIdx.x];
      atomicAdd(&pooled_p[(blockIdx.x & 63) * 128 + threadIdx.x], s);
    }
  }
}

// ================== final: reduce 64x128 partials + fc + sigmoid ============
__global__ __launch_bounds__(128)
void k_final(const float* __restrict__ pooled_p, const float* __restrict__ fcw,
             const float* __restrict__ fcb, float* __restrict__ out) {
  __shared__ float s[128];
  int t = threadIdx.x;
  float acc = 0.f;
#pragma unroll 8
  for (int k = 0; k < 64; ++k) acc += pooled_p[k * 128 + t];
  s[t] = acc * (1.0f / (float)NNODES) * fcw[t];
  __syncthreads();
  if (t == 0) {
    float v = 0.f;
    for (int i = 0; i < 128; ++i) v += s[i];
    v += fcb[0];
    out[0] = 1.f / (1.f + expf(-v));
  }
}

// ============================================================================
extern "C" void kernel_launch(void* const* d_in, const int* in_sizes, int n_in,
                              void* d_out, int out_size, void* d_ws, size_t ws_size,
                              hipStream_t stream) {
  const float* in_feat = (const float*)d_in[0];
  const float* W1      = (const float*)d_in[1];
  const float* W1s     = (const float*)d_in[2];
  const float* b1      = (const float*)d_in[3];
  const float* W2      = (const float*)d_in[4];
  const float* W2s     = (const float*)d_in[5];
  const float* b2      = (const float*)d_in[6];
  const float* fcw     = (const float*)d_in[7];
  const float* fcb     = (const float*)d_in[8];
  const int*   src     = (const int*)d_in[9];
  const int*   dst     = (const int*)d_in[10];
  const int*   et      = (const int*)d_in[11];
  float* out = (float*)d_out;

  // Workspace (~100 MB)
  unsigned char* xrs = (unsigned char*)d_ws;              // [50000][1152] fp8
  ushort* feat0 = (ushort*)(xrs + (size_t)NNODES * NOUT); // [50000][128] bf16
  ushort* h1    = feat0 + (size_t)NNODES * F;             // [50000][128]
  ushort* Wt1   = h1 + (size_t)NNODES * F;                // [1152][128]
  ushort* Wt2   = Wt1 + (size_t)NOUT * F;                 // [1152][128]
  float* pooled_p = (float*)(Wt2 + (size_t)NOUT * F);     // [64][128] } one
  int*   bcnt   = (int*)(pooled_p + 64 * 128);            // [NBKT]    } memset
  int*   bcur   = bcnt + NBKT;                            // [NBKT]    } memset
  int*   rowptr = bcur + NBKT;                            // [NNODES+1]
  int*   ebuf   = rowptr + NNODES + 2;                    // [NBKT*SEG]
  int*   edata  = ebuf + NBKT * SEG;                      // [NEDGES]

  // single memset: pooled_p + bcnt + bcur
  hipMemsetAsync(pooled_p, 0, (64 * 128 + 2 * NBKT) * sizeof(float), stream);

  // fused prep: coarse hist | feat cvt | weight prep x2
  k_prep<<<PREP_CHIST + PREP_CVT + 2 * PREP_W, 256, 0, stream>>>(
      dst, bcnt, in_feat, feat0, W1, W1s, Wt1, W2, W2s, Wt2);

  const int aggBlocks = NNODES / 4;                    // 12500

  // Layer 1 GEMM with CSR-scatter fused (scatter hidden under GEMM)
  gemm_xrs<<<CSR_BLOCKS + GEMM_BLOCKS, 512, 0, stream>>>(
      feat0, Wt1, xrs, 1, src, dst, et, bcur, ebuf);
  k_fsort<<<NBKT, 256, 0, stream>>>(ebuf, bcnt, rowptr, edata);
  k_aggregate<<<aggBlocks, 256, 0, stream>>>(xrs, rowptr, edata, b1, h1, nullptr);
  // Layer 2 (pooling fused into aggregate; h2 never materialized)
  gemm_xrs<<<GEMM_BLOCKS, 512, 0, stream>>>(
      h1, Wt2, xrs, 0, src, dst, et, bcur, ebuf);
  k_aggregate<<<aggBlocks, 256, 0, stream>>>(xrs, rowptr, edata, b2, nullptr, pooled_p);

  // Reduce partials + fc + sigmoid
  k_final<<<1, 128, 0, stream>>>(pooled_p, fcw, fcb, out);
}